// Round 5
// baseline (508.673 us; speedup 1.0000x reference)
//
#include <hip/hip_runtime.h>
#include <hip/hip_bf16.h>
#include <math.h>

#define HD   512
#define D2   1024
#define SEQ  4096
#define BAT  16

typedef _Float16 half8  __attribute__((ext_vector_type(8)));
typedef float    f32x4  __attribute__((ext_vector_type(4)));
typedef float    f32x16 __attribute__((ext_vector_type(16)));
typedef __attribute__((address_space(3))) void lds_void_t;
typedef __attribute__((address_space(1))) void glb_void_t;

// ---------- kernel 0: W bottom-half -> f16, DMA-order chunk-major ----------
// WtS half8-chunk idx: (kt*4 + kc)*512 + n ; value[j] = Wbot[kt*32+kc*8+j][n]
// -> fused kernel's B staging is a LINEAR global_load_lds whose LDS image is
//    exactly the B-frag layout (kc = q*2 + lhi), conflict-free b128 reads.
__global__ void wconv_kernel(const float* __restrict__ W, _Float16* __restrict__ WtS) {
  const int kt = blockIdx.x;       // 0..31
  const int t  = threadIdx.x;      // 256
  #pragma unroll
  for (int kc = 0; kc < 4; ++kc)
    #pragma unroll
    for (int nn = 0; nn < 2; ++nn) {
      const int n = nn * 256 + t;
      half8 h;
      #pragma unroll
      for (int j = 0; j < 8; ++j)
        h[j] = (_Float16)W[(size_t)(D2 + kt * 32 + kc * 8 + j) * HD + n];
      *(half8*)(WtS + ((size_t)(kt * 4 + kc) * 512 + n) * 8) = h;
    }
}

// ---------- kernel 1: h_proj[b,h] = hidden[b,:] . W_top[:,h] (atomic) ----------
__global__ void hproj_kernel(const float* __restrict__ hidden,
                             const float* __restrict__ W,
                             float* __restrict__ hproj) {
  const int b  = blockIdx.x >> 3;
  const int kc = blockIdx.x & 7;
  const int h  = threadIdx.x;
  float a0 = 0.f, a1 = 0.f;
  #pragma unroll 4
  for (int i = 0; i < 128; ++i) {
    const int d = kc * 128 + i;
    const float hd = hidden[b * D2 + d];
    a0 += hd * W[(size_t)d * HD + h];
    a1 += hd * W[(size_t)d * HD + h + 256];
  }
  atomicAdd(&hproj[b * HD + h], a0);
  atomicAdd(&hproj[b * HD + h + 256], a1);
}

// ---------- kernel 2 (fused): scores -> exp -> unnormalized context ----------
// 512 threads / 8 waves. Block tile 128s x 512n (FULL n). Wave 64x128:
// Fm=2 (wy), Fn=4 (wx quarter), mfma_f32_32x32x16_f16, acc 128 regs.
// K-loop rendezvous: raw s_barrier with s_waitcnt vmcnt(2) lgkmcnt(0) --
// B-DMA (issued 1 kt early, pinned oldest via sched_barrier) is retired,
// the 2 newest A-loads (issued 2 kt early) stay IN FLIGHT across the barrier.
// Then: local exp (C=0 safe: |score| <= sum|w_v| ~ 18) + context partial
// accumulated from the block's own enc tile (L2/L3-warm re-read).
__global__ __launch_bounds__(512, 2) void fused_kernel(
    const float* __restrict__ enc, const _Float16* __restrict__ WtS,
    const float* __restrict__ hproj, const float* __restrict__ b_attn,
    const float* __restrict__ w_v, float* __restrict__ ctx,
    float* __restrict__ sumexp)
{
  __shared__ __align__(16) _Float16 As[2][4 * 128 * 8];   // 8 KB per buf
  __shared__ __align__(16) _Float16 Bs[2][4 * 512 * 8];   // 32 KB per buf
  __shared__ float s_sc[128];
  __shared__ float s_w[128];

  const int s0  = blockIdx.x * 128;
  const int b   = blockIdx.y;
  const int tid = threadIdx.x, lane = tid & 63, w = tid >> 6;
  const int wy  = w >> 2, wx = w & 3;
  const int llo = lane & 31, lhi = lane >> 5;

  const float* encB = enc + ((size_t)b * SEQ + s0) * D2;

  // A staging: thread t loads 8 f32 of row (t>>2), k-chunk (t&3)
  const int arow = tid >> 2, akc = tid & 3;
  const float* aSrc = encB + (size_t)arow * D2 + akc * 8;

  f32x16 acc[2][4];
  #pragma unroll
  for (int mi = 0; mi < 2; ++mi)
    #pragma unroll
    for (int nf = 0; nf < 4; ++nf)
      acc[mi][nf] = (f32x16)(0.f);

  f32x4 R[2][2];   // 2-deep A prefetch ring (8 f32 each)

  auto loadA = [&](int kt, int slot) {
    const float* p = aSrc + kt * 32;
    R[slot][0] = *(const f32x4*)(p);
    R[slot][1] = *(const f32x4*)(p + 4);
  };
  auto storeA = [&](int buf, int slot) {
    half8 h;
    #pragma unroll
    for (int j = 0; j < 4; ++j) {
      h[j] = (_Float16)R[slot][0][j]; h[4 + j] = (_Float16)R[slot][1][j];
    }
    *(half8*)&As[buf][(akc * 128 + arow) * 8] = h;
  };
  auto issueB = [&](int kt, int buf) {
    #pragma unroll
    for (int i = 0; i < 4; ++i) {
      const int c = i * 512 + tid;
      __builtin_amdgcn_global_load_lds(
          (glb_void_t*)(WtS + ((size_t)kt * 2048 + c) * 8),
          (lds_void_t*)((char*)&Bs[buf][0] + c * 16), 16, 0, 0);
    }
  };
  auto compute = [&](int cur) {
    #pragma unroll
    for (int q = 0; q < 2; ++q) {
      half8 aq[2], bq[4];
      #pragma unroll
      for (int mi = 0; mi < 2; ++mi)
        aq[mi] = *(const half8*)&As[cur][((q * 2 + lhi) * 128 + wy * 64 + mi * 32 + llo) * 8];
      #pragma unroll
      for (int nf = 0; nf < 4; ++nf)
        bq[nf] = *(const half8*)&Bs[cur][((q * 2 + lhi) * 512 + wx * 128 + nf * 32 + llo) * 8];
      #pragma unroll
      for (int nf = 0; nf < 4; ++nf)
        #pragma unroll
        for (int mi = 0; mi < 2; ++mi)
          acc[mi][nf] = __builtin_amdgcn_mfma_f32_32x32x16_f16(aq[mi], bq[nf], acc[mi][nf], 0, 0, 0);
    }
  };
  auto step = [&](int kt, int cur) {
    const int nxt = cur ^ 1;
    if (kt + 1 < 32) issueB(kt + 1, nxt);     // B oldest in vm FIFO this iter
    __builtin_amdgcn_sched_barrier(0);        // pin: A-loads must stay after B-DMA
    if (kt + 1 < 32) storeA(nxt, nxt);        // cvt waits (partial vmcnt) on A(kt+1)
    if (kt + 3 < 32) loadA(kt + 3, nxt);      // refill ring: A(kt+3)
    compute(cur);
    if (kt < 29)   // B(kt+1) retired; 2 newest (A-loads) stay outstanding
      asm volatile("s_waitcnt vmcnt(2) lgkmcnt(0)\n\ts_barrier" ::: "memory");
    else           // tail: no A-loads issued after B -> full drain
      asm volatile("s_waitcnt vmcnt(0) lgkmcnt(0)\n\ts_barrier" ::: "memory");
  };

  // prologue: buf0 staged; ring holds A(1),A(2); s_sc zeroed
  if (tid < 128) s_sc[tid] = 0.f;
  issueB(0, 0);
  loadA(0, 0);
  storeA(0, 0);
  loadA(1, 1);
  loadA(2, 0);
  asm volatile("s_waitcnt lgkmcnt(0)\n\ts_barrier" ::: "memory");

  for (int kt2 = 0; kt2 < 16; ++kt2) {
    step(2 * kt2,     0);
    step(2 * kt2 + 1, 1);
  }

  // ---- epilogue: tanh + dot(w_v) -> per-row score partials -> LDS ----
  // D layout (32x32): col n = llo, row = (r&3) + 8*(r>>2) + 4*lhi  [R3/R4-verified]
  float p[2][16];
  #pragma unroll
  for (int mi = 0; mi < 2; ++mi)
    #pragma unroll
    for (int r = 0; r < 16; ++r) p[mi][r] = 0.f;

  #pragma unroll
  for (int nf = 0; nf < 4; ++nf) {
    const int n = wx * 128 + nf * 32 + llo;
    const float hb = hproj[b * HD + n] + b_attn[n];
    const float wv = w_v[n];
    #pragma unroll
    for (int mi = 0; mi < 2; ++mi)
      #pragma unroll
      for (int r = 0; r < 16; ++r) {
        float x = fminf(fmaxf(acc[mi][nf][r] + hb, -15.f), 15.f);
        float ex = __expf(2.f * x);
        p[mi][r] += wv * __fdividef(ex - 1.f, ex + 1.f);
      }
  }
  #pragma unroll
  for (int off = 1; off <= 16; off <<= 1)
    #pragma unroll
    for (int mi = 0; mi < 2; ++mi)
      #pragma unroll
      for (int r = 0; r < 16; ++r)
        p[mi][r] += __shfl_xor(p[mi][r], off, 64);

  if (llo == 0) {
    #pragma unroll
    for (int mi = 0; mi < 2; ++mi)
      #pragma unroll
      for (int r = 0; r < 16; ++r) {
        const int m = wy * 64 + mi * 32 + (r & 3) + 8 * (r >> 2) + 4 * lhi;
        atomicAdd(&s_sc[m], p[mi][r]);   // 4 contenders (wx)
      }
  }
  __syncthreads();

  // ---- exp weights (C=0, overflow-safe) + block sum-exp ----
  if (tid < 128) s_w[tid] = __expf(s_sc[tid]);
  __syncthreads();
  if (tid < 64) {
    float v = s_w[tid] + s_w[tid + 64];
    #pragma unroll
    for (int off = 32; off >= 1; off >>= 1) v += __shfl_xor(v, off, 64);
    if (tid == 0) atomicAdd(&sumexp[b], v);
  }

  // ---- phase 2: unnormalized context partial from own (L2/L3-warm) tile ----
  const int tg = tid >> 7, cb = (tid & 127) * 8;
  const float* pr = encB + (size_t)tg * 32 * D2 + cb;
  const float* wp = &s_w[tg * 32];
  f32x4 c0a = {0.f,0.f,0.f,0.f}, c0b = {0.f,0.f,0.f,0.f};
  f32x4 c1a = {0.f,0.f,0.f,0.f}, c1b = {0.f,0.f,0.f,0.f};
  #pragma unroll 4
  for (int i = 0; i < 32; i += 2) {
    const float w0 = wp[i], w1 = wp[i + 1];
    c0a += w0 * *(const f32x4*)(pr + (size_t)i * D2);
    c0b += w0 * *(const f32x4*)(pr + (size_t)i * D2 + 4);
    c1a += w1 * *(const f32x4*)(pr + (size_t)(i + 1) * D2);
    c1b += w1 * *(const f32x4*)(pr + (size_t)(i + 1) * D2 + 4);
  }
  c0a += c1a; c0b += c1b;
  float* cp = ctx + b * D2 + cb;
  #pragma unroll
  for (int j = 0; j < 4; ++j) {
    atomicAdd(cp + j,     c0a[j]);
    atomicAdd(cp + 4 + j, c0b[j]);
  }
}

// ---------- kernel 3: out = ctx / sumexp ----------
__global__ void norm_kernel(const float* __restrict__ ctx,
                            const float* __restrict__ sumexp,
                            float* __restrict__ out) {
  const int b = blockIdx.x, t = threadIdx.x;   // 256
  const float inv = 1.0f / sumexp[b];
  f32x4 v = *(const f32x4*)(ctx + b * D2 + t * 4);
  v *= inv;
  *(f32x4*)(out + b * D2 + t * 4) = v;
}

extern "C" void kernel_launch(void* const* d_in, const int* in_sizes, int n_in,
                              void* d_out, int out_size, void* d_ws, size_t ws_size,
                              hipStream_t stream) {
  (void)in_sizes; (void)n_in; (void)ws_size; (void)out_size;
  const float* hidden = (const float*)d_in[0];   // [16,1024]
  const float* enc    = (const float*)d_in[1];   // [16,4096,1024]
  const float* W      = (const float*)d_in[2];   // [2048,512]
  const float* b_attn = (const float*)d_in[3];   // [512]
  const float* w_v    = (const float*)d_in[4];   // [512]
  float* out = (float*)d_out;                    // [16,1024]

  char* ws = (char*)d_ws;
  _Float16* WtS = (_Float16*)ws;                        // 1 MB shuffled Wbot f16
  float* hproj  = (float*)(ws + (1 << 20));             // 32 KB
  float* ctx    = (float*)(ws + (1 << 20) + 32768);     // 64 KB [16][1024]
  float* sumexp = (float*)(ws + (1 << 20) + 32768 + 65536);  // 64 B [16]

  hipMemsetAsync(hproj,  0, BAT * HD * sizeof(float), stream);
  hipMemsetAsync(ctx,    0, BAT * D2 * sizeof(float), stream);
  hipMemsetAsync(sumexp, 0, BAT * sizeof(float), stream);

  wconv_kernel <<<dim3(32),           256, 0, stream>>>(W, WtS);
  hproj_kernel <<<dim3(128),          256, 0, stream>>>(hidden, W, hproj);
  fused_kernel <<<dim3(SEQ / 128, BAT), 512, 0, stream>>>(enc, WtS, hproj, b_attn, w_v, ctx, sumexp);
  norm_kernel  <<<dim3(BAT),          256, 0, stream>>>(ctx, sumexp, out);
}